// Round 2
// baseline (220.804 us; speedup 1.0000x reference)
//
#include <hip/hip_runtime.h>
#include <math.h>

#define NCL  27
#define CCH  512
#define HWPX 9216            // 96*96
#define NB   16
#define NPIX (NB * HWPX)     // 147456
#define EPSN 1e-12f

// ---------------------------------------------------------------------------
// k0: per-cluster inverse L2 norm (27 rows of 512) + zero the loss accumulator
// ---------------------------------------------------------------------------
__global__ __launch_bounds__(64) void k0_prep(const float* __restrict__ cl,
                                              float* __restrict__ inv_cln,
                                              float* __restrict__ loss_acc) {
    const int n = blockIdx.x;
    const int t = threadIdx.x;
    const float* row = cl + n * CCH;
    float ss = 0.f;
#pragma unroll
    for (int i = 0; i < CCH / 64; ++i) {
        float v = row[i * 64 + t];
        ss = fmaf(v, v, ss);
    }
#pragma unroll
    for (int off = 32; off > 0; off >>= 1)
        ss += __shfl_xor(ss, off, 64);
    if (t == 0) {
        inv_cln[n] = 1.0f / fmaxf(sqrtf(ss), EPSN);
        if (n == 0) loss_acc[0] = 0.f;
    }
}

// ---------------------------------------------------------------------------
// k1: fused main kernel, 1 thread / pixel.
//  - 16-wide channel chunks, double-buffered: chunk k+1's 16 loads stay in
//    flight (vmcnt(16)) while chunk k's 27x16 FMAs run -> latency hidden.
//  - cluster reads wave-uniform -> scalar loads (SGPR path, free on VALU).
// ---------------------------------------------------------------------------
__global__ __launch_bounds__(256) void k1_main(const float* __restrict__ x,
                                               const float* __restrict__ cl,
                                               const float* __restrict__ alpha_p,
                                               const float* __restrict__ inv_cln,
                                               float* __restrict__ out,
                                               float* __restrict__ loss_acc) {
    const int p  = blockIdx.x * 256 + threadIdx.x;
    const int b  = p / HWPX;                       // uniform within a block
    const int hw = p - b * HWPX;
    const float* xb = x + (size_t)b * (CCH * HWPX) + hw;

    float acc[NCL];
#pragma unroll
    for (int n = 0; n < NCL; ++n) acc[n] = 0.f;
    float ss = 0.f;

    float xa[16], xv[16];

    // prologue: preload chunk 0 into xa
#pragma unroll
    for (int i = 0; i < 16; ++i)
        xa[i] = xb[(size_t)i * HWPX];

    // main loop: 2 chunks per iteration, ping-pong xa/xv (all static indices)
    for (int c0 = 0; c0 < CCH; c0 += 32) {
        // issue loads for chunk c0+16 into xv (in flight during compute on xa)
#pragma unroll
        for (int i = 0; i < 16; ++i)
            xv[i] = xb[(size_t)(c0 + 16 + i) * HWPX];

        // compute chunk c0 from xa
#pragma unroll
        for (int i = 0; i < 16; ++i)
            ss = fmaf(xa[i], xa[i], ss);
#pragma unroll
        for (int n = 0; n < NCL; ++n) {
            const float* cr = cl + n * CCH + c0;   // wave-uniform -> s_load
            float a = acc[n];
#pragma unroll
            for (int i = 0; i < 16; ++i)
                a = fmaf(xa[i], cr[i], a);
            acc[n] = a;
        }

        // issue loads for chunk c0+32 into xa (in flight during compute on xv)
        if (c0 + 32 < CCH) {
#pragma unroll
            for (int i = 0; i < 16; ++i)
                xa[i] = xb[(size_t)(c0 + 32 + i) * HWPX];
        }

        // compute chunk c0+16 from xv
#pragma unroll
        for (int i = 0; i < 16; ++i)
            ss = fmaf(xv[i], xv[i], ss);
#pragma unroll
        for (int n = 0; n < NCL; ++n) {
            const float* cr = cl + n * CCH + c0 + 16;
            float a = acc[n];
#pragma unroll
            for (int i = 0; i < 16; ++i)
                a = fmaf(xv[i], cr[i], a);
            acc[n] = a;
        }
    }

    const float inv_x = 1.0f / fmaxf(sqrtf(ss), EPSN);
    const float alpha = alpha_p[0];

    float ip[NCL];
    float m = -1e30f;
#pragma unroll
    for (int n = 0; n < NCL; ++n) {
        ip[n] = acc[n] * inv_cln[n] * inv_x;       // cosine similarity
        float s = ip[n] * alpha;
        acc[n] = s;
        m = fmaxf(m, s);
    }
    float sum = 0.f;
#pragma unroll
    for (int n = 0; n < NCL; ++n) {
        float e = __expf(acc[n] - m);
        acc[n] = e;
        sum += e;
    }
    const float inv_sum = 1.0f / sum;

    float lterm = 0.f;
    float* ob = out + 1 + (size_t)b * (NCL * HWPX) + hw;
#pragma unroll
    for (int n = 0; n < NCL; ++n) {
        float pr = acc[n] * inv_sum;
        ob[(size_t)n * HWPX] = pr;                 // coalesced per n
        lterm = fmaf(pr, ip[n], lterm);
    }

    // block-level loss reduction, one atomic per block
#pragma unroll
    for (int off = 32; off > 0; off >>= 1)
        lterm += __shfl_down(lterm, off, 64);
    __shared__ float wsum[4];
    const int lane = threadIdx.x & 63;
    const int wid  = threadIdx.x >> 6;
    if (lane == 0) wsum[wid] = lterm;
    __syncthreads();
    if (threadIdx.x == 0)
        atomicAdd(loss_acc, wsum[0] + wsum[1] + wsum[2] + wsum[3]);
}

// ---------------------------------------------------------------------------
// k2: finalize loss
// ---------------------------------------------------------------------------
__global__ void k2_fin(const float* __restrict__ loss_acc,
                       float* __restrict__ out) {
    out[0] = -loss_acc[0] * (1.0f / (float)NPIX);
}

extern "C" void kernel_launch(void* const* d_in, const int* in_sizes, int n_in,
                              void* d_out, int out_size, void* d_ws, size_t ws_size,
                              hipStream_t stream) {
    const float* x     = (const float*)d_in[0];
    const float* cl    = (const float*)d_in[1];
    const float* alpha = (const float*)d_in[2];
    float* out = (float*)d_out;
    float* ws  = (float*)d_ws;

    float* inv_cln  = ws;        // 27 floats
    float* loss_acc = ws + 32;   // 1 float

    hipLaunchKernelGGL(k0_prep, dim3(NCL), dim3(64), 0, stream, cl, inv_cln, loss_acc);
    hipLaunchKernelGGL(k1_main, dim3(NPIX / 256), dim3(256), 0, stream,
                       x, cl, alpha, inv_cln, out, loss_acc);
    hipLaunchKernelGGL(k2_fin, dim3(1), dim3(1), 0, stream, loss_acc, out);
}

// Round 3
// 157.691 us; speedup vs baseline: 1.4002x; 1.4002x over previous
//
#include <hip/hip_runtime.h>
#include <math.h>

#define NCL  27
#define CCH  512
#define HWPX 9216            // 96*96
#define NB   16
#define NPIX (NB * HWPX)     // 147456
#define EPSN 1e-12f
#define PXB  64              // pixels per block
#define CPW  128             // channels per wave (512 / 4 waves)

// ---------------------------------------------------------------------------
// k0: per-cluster inverse L2 norm (27 rows of 512) + zero the loss accumulator
// ---------------------------------------------------------------------------
__global__ __launch_bounds__(64) void k0_prep(const float* __restrict__ cl,
                                              float* __restrict__ inv_cln,
                                              float* __restrict__ loss_acc) {
    const int n = blockIdx.x;
    const int t = threadIdx.x;
    const float* row = cl + n * CCH;
    float ss = 0.f;
#pragma unroll
    for (int i = 0; i < CCH / 64; ++i) {
        float v = row[i * 64 + t];
        ss = fmaf(v, v, ss);
    }
#pragma unroll
    for (int off = 32; off > 0; off >>= 1)
        ss += __shfl_xor(ss, off, 64);
    if (t == 0) {
        inv_cln[n] = 1.0f / fmaxf(sqrtf(ss), EPSN);
        if (n == 0) loss_acc[0] = 0.f;
    }
}

// ---------------------------------------------------------------------------
// k1: fused main kernel.
//  Block = 256 threads = 4 waves, covers 64 pixels.
//  Wave w computes partial dots over channels [w*128, w*128+128).
//  -> grid = 2304 blocks (9/CU), ~28 waves/CU resident (LDS-capped at 7 blk)
//  Cross-wave reduce in LDS; wave 0 does softmax + stores + loss.
//  Cluster reads forced scalar via readfirstlane(waveid).
// ---------------------------------------------------------------------------
__global__ __launch_bounds__(256) void k1_main(const float* __restrict__ x,
                                               const float* __restrict__ cl,
                                               const float* __restrict__ alpha_p,
                                               const float* __restrict__ inv_cln,
                                               float* __restrict__ out,
                                               float* __restrict__ loss_acc) {
    const int tid = threadIdx.x;
    const int l   = tid & 63;                         // lane -> pixel in group
    const int w   = tid >> 6;                         // wave -> channel chunk
    const int wu  = __builtin_amdgcn_readfirstlane(w); // provably uniform
    const int p0  = blockIdx.x * PXB;                 // first pixel of group
    const int b   = p0 / HWPX;                        // uniform (64 | 9216)
    const int hw  = p0 - b * HWPX + l;                // per-lane pixel offset

    const float* xb  = x + (size_t)b * (CCH * HWPX)
                         + (size_t)(wu * CPW) * HWPX + hw;
    const float* clw = cl + wu * CPW;                 // uniform -> s_load

    float acc[NCL];
#pragma unroll
    for (int n = 0; n < NCL; ++n) acc[n] = 0.f;
    float ss = 0.f;

    for (int c0 = 0; c0 < CPW; c0 += 16) {
        float xv[16];
#pragma unroll
        for (int i = 0; i < 16; ++i)
            xv[i] = xb[(size_t)(c0 + i) * HWPX];      // coalesced 256B
#pragma unroll
        for (int i = 0; i < 16; ++i)
            ss = fmaf(xv[i], xv[i], ss);
#pragma unroll
        for (int n = 0; n < NCL; ++n) {
            const float* cr = clw + n * CCH + c0;     // wave-uniform
            float a = acc[n];
#pragma unroll
            for (int i = 0; i < 16; ++i)
                a = fmaf(xv[i], cr[i], a);
            acc[n] = a;
        }
    }

    // ---- cross-wave reduction: waves 1..3 dump partials, wave 0 sums ----
    __shared__ float red[3][NCL + 1][64];             // 21504 B
    if (w != 0) {
#pragma unroll
        for (int n = 0; n < NCL; ++n)
            red[w - 1][n][l] = acc[n];                // lane-consecutive
        red[w - 1][NCL][l] = ss;
    }
    __syncthreads();
    if (w != 0) return;                               // no barriers below

#pragma unroll
    for (int n = 0; n < NCL; ++n)
        acc[n] += red[0][n][l] + red[1][n][l] + red[2][n][l];
    ss += red[0][NCL][l] + red[1][NCL][l] + red[2][NCL][l];

    // ---- epilogue: cosine, softmax, store, loss (wave 0 only) ----
    const float inv_x = 1.0f / fmaxf(sqrtf(ss), EPSN);
    const float alpha = alpha_p[0];

    float ip[NCL];
    float m = -1e30f;
#pragma unroll
    for (int n = 0; n < NCL; ++n) {
        ip[n] = acc[n] * inv_cln[n] * inv_x;
        float s = ip[n] * alpha;
        acc[n] = s;
        m = fmaxf(m, s);
    }
    float sum = 0.f;
#pragma unroll
    for (int n = 0; n < NCL; ++n) {
        float e = __expf(acc[n] - m);
        acc[n] = e;
        sum += e;
    }
    const float inv_sum = 1.0f / sum;

    float lterm = 0.f;
    float* ob = out + 1 + (size_t)b * (NCL * HWPX) + (p0 - b * HWPX) + l;
#pragma unroll
    for (int n = 0; n < NCL; ++n) {
        float pr = acc[n] * inv_sum;
        ob[(size_t)n * HWPX] = pr;                    // coalesced 256B
        lterm = fmaf(pr, ip[n], lterm);
    }

#pragma unroll
    for (int off = 32; off > 0; off >>= 1)
        lterm += __shfl_down(lterm, off, 64);
    if (l == 0)
        atomicAdd(loss_acc, lterm);
}

// ---------------------------------------------------------------------------
// k2: finalize loss
// ---------------------------------------------------------------------------
__global__ void k2_fin(const float* __restrict__ loss_acc,
                       float* __restrict__ out) {
    out[0] = -loss_acc[0] * (1.0f / (float)NPIX);
}

extern "C" void kernel_launch(void* const* d_in, const int* in_sizes, int n_in,
                              void* d_out, int out_size, void* d_ws, size_t ws_size,
                              hipStream_t stream) {
    const float* x     = (const float*)d_in[0];
    const float* cl    = (const float*)d_in[1];
    const float* alpha = (const float*)d_in[2];
    float* out = (float*)d_out;
    float* ws  = (float*)d_ws;

    float* inv_cln  = ws;        // 27 floats
    float* loss_acc = ws + 32;   // 1 float

    hipLaunchKernelGGL(k0_prep, dim3(NCL), dim3(64), 0, stream, cl, inv_cln, loss_acc);
    hipLaunchKernelGGL(k1_main, dim3(NPIX / PXB), dim3(256), 0, stream,
                       x, cl, alpha, inv_cln, out, loss_acc);
    hipLaunchKernelGGL(k2_fin, dim3(1), dim3(1), 0, stream, loss_acc, out);
}

// Round 4
// 134.073 us; speedup vs baseline: 1.6469x; 1.1762x over previous
//
#include <hip/hip_runtime.h>
#include <math.h>

#define NCL  27
#define CCH  512
#define HWPX 9216            // 96*96
#define NB   16
#define NPIX (NB * HWPX)     // 147456
#define EPSN 1e-12f
#define PXT  256             // pixels per block tile (divides HWPX: 9216=36*256)
#define CHK  16              // channels per staged chunk
#define NCHK (CCH / CHK)     // 32 chunks

typedef float v2f __attribute__((ext_vector_type(2)));

// fire-and-forget global->LDS DMA: 16 B/lane, LDS dest = uniform base + lane*16
__device__ __forceinline__ void gload_lds16(const float* g, float* lds) {
    __builtin_amdgcn_global_load_lds(
        (const __attribute__((address_space(1))) unsigned int*)g,
        (__attribute__((address_space(3))) unsigned int*)lds,
        16, 0, 0);
}

// ---------------------------------------------------------------------------
// k0: per-cluster inverse L2 norm + zero loss accumulator
// ---------------------------------------------------------------------------
__global__ __launch_bounds__(64) void k0_prep(const float* __restrict__ cl,
                                              float* __restrict__ inv_cln,
                                              float* __restrict__ loss_acc) {
    const int n = blockIdx.x;
    const int t = threadIdx.x;
    const float* row = cl + n * CCH;
    float ss = 0.f;
#pragma unroll
    for (int i = 0; i < CCH / 64; ++i) {
        float v = row[i * 64 + t];
        ss = fmaf(v, v, ss);
    }
#pragma unroll
    for (int off = 32; off > 0; off >>= 1)
        ss += __shfl_xor(ss, off, 64);
    if (t == 0) {
        inv_cln[n] = 1.0f / fmaxf(sqrtf(ss), EPSN);
        if (n == 0) loss_acc[0] = 0.f;
    }
}

// ---------------------------------------------------------------------------
// k1: fused main kernel.
//  Block = 256 thr = 4 waves = 256-pixel tile; wave w owns px 64w..64w+63,
//  each lane owns ONE pixel end-to-end (full 512-ch dot, softmax, store).
//  x staged through LDS with the 2-phase template: stage(t+1) issued before
//  compute(t); one vmcnt-draining __syncthreads per chunk -> 16 KB in flight
//  per block throughout compute -> HBM saturation at 2.25 blocks/CU.
//  Clusters read via wave-uniform s_loads; FMAs channel-paired (v_pk_fma_f32).
// ---------------------------------------------------------------------------
__global__ __launch_bounds__(256) void k1_main(const float* __restrict__ x,
                                               const float* __restrict__ cl,
                                               const float* __restrict__ alpha_p,
                                               const float* __restrict__ inv_cln,
                                               float* __restrict__ out,
                                               float* __restrict__ loss_acc) {
    __shared__ float tile[2][CHK][PXT];               // 32 KB

    const int tid = threadIdx.x;
    const int l   = tid & 63;
    const int w   = tid >> 6;                         // wave 0..3
    const int p0  = blockIdx.x * PXT;
    const int b   = p0 / HWPX;                        // uniform (256 | 9216)
    const int hw0 = p0 - b * HWPX;
    const int px  = (w << 6) + l;                     // pixel in tile, 0..255

    // staging source: wave w stages channel rows (4w+r) of each chunk,
    // lane covers 4 consecutive pixels (16 B)
    const float* xg = x + (size_t)b * CCH * HWPX + hw0;
    const float* gw = xg + (size_t)(4 * w) * HWPX + 4 * l;

    v2f acc2[NCL];
#pragma unroll
    for (int n = 0; n < NCL; ++n) acc2[n] = (v2f){0.f, 0.f};
    v2f ss2 = (v2f){0.f, 0.f};

    // prologue: stage chunk 0 into buf 0
#pragma unroll
    for (int r = 0; r < 4; ++r)
        gload_lds16(gw + (size_t)r * HWPX, &tile[0][4 * w + r][0]);
    __syncthreads();

    int buf = 0;
    for (int t = 0; t < NCHK; ++t) {
        // issue next chunk's staging (stays in flight during compute)
        if (t + 1 < NCHK) {
            const float* gc = gw + (size_t)(t + 1) * CHK * HWPX;
#pragma unroll
            for (int r = 0; r < 4; ++r)
                gload_lds16(gc + (size_t)r * HWPX, &tile[buf ^ 1][4 * w + r][0]);
        }

        // compute chunk t from tile[buf]
        float xv[CHK];
#pragma unroll
        for (int i = 0; i < CHK; ++i)
            xv[i] = tile[buf][i][px];                 // ds_read_b32, 2-way free
        v2f xp[CHK / 2];
#pragma unroll
        for (int i = 0; i < CHK / 2; ++i)
            xp[i] = (v2f){xv[2 * i], xv[2 * i + 1]};
#pragma unroll
        for (int i = 0; i < CHK / 2; ++i)
            ss2 = __builtin_elementwise_fma(xp[i], xp[i], ss2);
        const int c0 = t * CHK;
#pragma unroll
        for (int n = 0; n < NCL; ++n) {
            const v2f* cr = (const v2f*)(cl + n * CCH + c0);  // uniform -> s_load
            v2f a = acc2[n];
#pragma unroll
            for (int i = 0; i < CHK / 2; ++i)
                a = __builtin_elementwise_fma(xp[i], cr[i], a);
            acc2[n] = a;
        }

        __syncthreads();   // drains stage(t+1); buffer t&1 safe to overwrite
        buf ^= 1;
    }

    // ---- epilogue: every lane owns its pixel ----
    const float ssum  = ss2.x + ss2.y;
    const float inv_x = 1.0f / fmaxf(sqrtf(ssum), EPSN);
    const float alpha = alpha_p[0];

    float ip[NCL], ex[NCL];
    float m = -1e30f;
#pragma unroll
    for (int n = 0; n < NCL; ++n) {
        ip[n] = (acc2[n].x + acc2[n].y) * inv_cln[n] * inv_x;
        float s = ip[n] * alpha;
        ex[n] = s;
        m = fmaxf(m, s);
    }
    float sum = 0.f;
#pragma unroll
    for (int n = 0; n < NCL; ++n) {
        float e = __expf(ex[n] - m);
        ex[n] = e;
        sum += e;
    }
    const float inv_sum = 1.0f / sum;

    float lterm = 0.f;
    float* ob = out + 1 + (size_t)b * (NCL * HWPX) + hw0 + px;
#pragma unroll
    for (int n = 0; n < NCL; ++n) {
        float pr = ex[n] * inv_sum;
        ob[(size_t)n * HWPX] = pr;                    // coalesced 256B/wave
        lterm = fmaf(pr, ip[n], lterm);
    }

    // per-wave loss reduction, one atomic per wave
#pragma unroll
    for (int off = 32; off > 0; off >>= 1)
        lterm += __shfl_down(lterm, off, 64);
    if (l == 0)
        atomicAdd(loss_acc, lterm);
}

// ---------------------------------------------------------------------------
// k2: finalize loss
// ---------------------------------------------------------------------------
__global__ void k2_fin(const float* __restrict__ loss_acc,
                       float* __restrict__ out) {
    out[0] = -loss_acc[0] * (1.0f / (float)NPIX);
}

extern "C" void kernel_launch(void* const* d_in, const int* in_sizes, int n_in,
                              void* d_out, int out_size, void* d_ws, size_t ws_size,
                              hipStream_t stream) {
    const float* x     = (const float*)d_in[0];
    const float* cl    = (const float*)d_in[1];
    const float* alpha = (const float*)d_in[2];
    float* out = (float*)d_out;
    float* ws  = (float*)d_ws;

    float* inv_cln  = ws;        // 27 floats
    float* loss_acc = ws + 32;   // 1 float

    hipLaunchKernelGGL(k0_prep, dim3(NCL), dim3(64), 0, stream, cl, inv_cln, loss_acc);
    hipLaunchKernelGGL(k1_main, dim3(NPIX / PXT), dim3(256), 0, stream,
                       x, cl, alpha, inv_cln, out, loss_acc);
    hipLaunchKernelGGL(k2_fin, dim3(1), dim3(1), 0, stream, loss_acc, out);
}